// Round 1
// baseline (1549.218 us; speedup 1.0000x reference)
//
#include <hip/hip_runtime.h>

#define B_ 4
#define H_ 256
#define W_ 256
#define Z_ 64
#define NB_ (H_*W_*Z_)      /* 4194304 */
#define N_  (B_*NB_)        /* 16777216 */
#define ITER_ 8
#define EPS_ 1e-6f
#define SLOTS_ 64

/* scal layout (floats) */
#define RHO_OFF   0
#define ETA_OFF   ((ITER_+1)*B_*SLOTS_)
#define LOSS_OFF  (ETA_OFF + ITER_*B_*SLOTS_)
#define MAXE_OFF  (LOSS_OFF + SLOTS_)
#define SCAL_FLOATS (MAXE_OFF + SLOTS_)

__device__ __forceinline__ float wsum(float v){
  v += __shfl_xor(v,32); v += __shfl_xor(v,16); v += __shfl_xor(v,8);
  v += __shfl_xor(v,4);  v += __shfl_xor(v,2);  v += __shfl_xor(v,1);
  return v;
}
__device__ __forceinline__ float wmaxr(float v){
  v = fmaxf(v,__shfl_xor(v,32)); v = fmaxf(v,__shfl_xor(v,16));
  v = fmaxf(v,__shfl_xor(v,8));  v = fmaxf(v,__shfl_xor(v,4));
  v = fmaxf(v,__shfl_xor(v,2));  v = fmaxf(v,__shfl_xor(v,1));
  return v;
}
/* every thread returns the full sum over the 64 slots */
__device__ __forceinline__ float read_sum(const float* s){
  return wsum(s[threadIdx.x & 63]);
}
__device__ __forceinline__ void block_atomic_sum(float v, float* dst, float* lds){
  v = wsum(v);
  int wid = threadIdx.x >> 6, lane = threadIdx.x & 63;
  if (lane == 0) lds[wid] = v;
  __syncthreads();
  if (threadIdx.x == 0) atomicAdd(dst, lds[0]+lds[1]+lds[2]+lds[3]);
}

__device__ __forceinline__ float4 ld4(const float* p){ return *(const float4*)p; }

/* stencil of a single array a; also returns center quad */
__device__ __forceinline__ void stencil1(const float* __restrict__ a, int base,
                                         int w, int h, int zq,
                                         float4& c, float4& st)
{
  c = ld4(a+base);
  float4 wm = make_float4(0,0,0,0), wp = wm, hm = wm, hp = wm;
  if (w > 0)     wm = ld4(a+base-Z_);
  if (w < W_-1)  wp = ld4(a+base+Z_);
  if (h > 0)     hm = ld4(a+base-W_*Z_);
  if (h < H_-1)  hp = ld4(a+base+W_*Z_);
  float zl = (zq > 0)  ? a[base-1] : 0.f;
  float zr = (zq < 15) ? a[base+4] : 0.f;
  st.x = 6.f*c.x - wm.x - wp.x - hm.x - hp.x - zl  - c.y;
  st.y = 6.f*c.y - wm.y - wp.y - hm.y - hp.y - c.x - c.z;
  st.z = 6.f*c.z - wm.z - wp.z - hm.z - hp.z - c.y - c.w;
  st.w = 6.f*c.w - wm.w - wp.w - hm.w - hp.w - c.z - zr;
}

/* stencil of v = r + beta*p (computed on the fly); also returns center v quad */
__device__ __forceinline__ float4 comb4(const float* r, const float* p, float beta, int idx){
  float4 a = ld4(r+idx), b = ld4(p+idx);
  a.x += beta*b.x; a.y += beta*b.y; a.z += beta*b.z; a.w += beta*b.w;
  return a;
}
__device__ __forceinline__ float comb1(const float* r, const float* p, float beta, int idx){
  return r[idx] + beta*p[idx];
}
__device__ __forceinline__ void stencil2(const float* __restrict__ r,
                                         const float* __restrict__ p, float beta,
                                         int base, int w, int h, int zq,
                                         float4& c, float4& st)
{
  c = comb4(r,p,beta,base);
  float4 wm = make_float4(0,0,0,0), wp = wm, hm = wm, hp = wm;
  if (w > 0)     wm = comb4(r,p,beta,base-Z_);
  if (w < W_-1)  wp = comb4(r,p,beta,base+Z_);
  if (h > 0)     hm = comb4(r,p,beta,base-W_*Z_);
  if (h < H_-1)  hp = comb4(r,p,beta,base+W_*Z_);
  float zl = (zq > 0)  ? comb1(r,p,beta,base-1) : 0.f;
  float zr = (zq < 15) ? comb1(r,p,beta,base+4) : 0.f;
  st.x = 6.f*c.x - wm.x - wp.x - hm.x - hp.x - zl  - c.y;
  st.y = 6.f*c.y - wm.y - wp.y - hm.y - hp.y - c.x - c.z;
  st.z = 6.f*c.z - wm.z - wp.z - hm.z - hp.z - c.y - c.w;
  st.w = 6.f*c.w - wm.w - wp.w - hm.w - hp.w - c.z - zr;
}

#define IDX_SETUP \
  const int zq = threadIdx.x & 15; \
  const int wl = threadIdx.x >> 4; \
  const int w  = blockIdx.x*16 + wl; \
  const int h  = blockIdx.y; \
  const int bb = blockIdx.z; \
  const int base = ((bb*H_ + h)*W_ + w)*Z_ + zq*4; \
  const int flat = (blockIdx.z*gridDim.y + blockIdx.y)*gridDim.x + blockIdx.x; \
  const int slot = flat & (SLOTS_-1);

/* r = b - A x ; rho0 = <r,r> per batch */
__global__ __launch_bounds__(256) void k_init(const float* __restrict__ x,
                                              const float* __restrict__ b,
                                              float* __restrict__ r,
                                              float* scal)
{
  __shared__ float lds[4];
  IDX_SETUP
  float4 c, st;
  stencil1(x, base, w, h, zq, c, st);
  float4 bv = ld4(b+base);
  float4 rv = make_float4(bv.x-st.x, bv.y-st.y, bv.z-st.z, bv.w-st.w);
  *(float4*)(r+base) = rv;
  float rho = rv.x*rv.x + rv.y*rv.y + rv.z*rv.z + rv.w*rv.w;
  block_atomic_sum(rho, scal + RHO_OFF + (0*B_+bb)*SLOTS_ + slot, lds);
}

/* p_new = r + beta*p_old ; eta = <p_new, A p_new> per batch */
__global__ __launch_bounds__(256) void k_a(const float* __restrict__ r,
                                           const float* __restrict__ pold,
                                           float* __restrict__ pnew,
                                           float* scal, int it, int is_first)
{
  __shared__ float lds[4];
  IDX_SETUP
  float beta = 0.f;
  if (!is_first) {
    float num = read_sum(scal + RHO_OFF + (it*B_+bb)*SLOTS_);
    float den = read_sum(scal + RHO_OFF + ((it-1)*B_+bb)*SLOTS_);
    beta = num / (den + EPS_);
  }
  float4 c, st;
  stencil2(r, pold, beta, base, w, h, zq, c, st);
  *(float4*)(pnew+base) = c;
  float eta = c.x*st.x + c.y*st.y + c.z*st.z + c.w*st.w;
  block_atomic_sum(eta, scal + ETA_OFF + (it*B_+bb)*SLOTS_ + slot, lds);
}

/* alpha = rho/(eta+eps); x += alpha p; r -= alpha*A p; rho_next = <r,r> */
__global__ __launch_bounds__(256) void k_b(float* __restrict__ x,
                                           float* __restrict__ r,
                                           const float* __restrict__ p,
                                           float* scal, int it)
{
  __shared__ float lds[4];
  IDX_SETUP
  float num = read_sum(scal + RHO_OFF + (it*B_+bb)*SLOTS_);
  float den = read_sum(scal + ETA_OFF + (it*B_+bb)*SLOTS_);
  float alpha = num / (den + EPS_);
  float4 c, st;
  stencil1(p, base, w, h, zq, c, st);
  float4 xv = ld4(x+base);
  xv.x += alpha*c.x; xv.y += alpha*c.y; xv.z += alpha*c.z; xv.w += alpha*c.w;
  *(float4*)(x+base) = xv;
  float4 rv = ld4(r+base);
  rv.x -= alpha*st.x; rv.y -= alpha*st.y; rv.z -= alpha*st.z; rv.w -= alpha*st.w;
  *(float4*)(r+base) = rv;
  float rho = rv.x*rv.x + rv.y*rv.y + rv.z*rv.z + rv.w*rv.w;
  block_atomic_sum(rho, scal + RHO_OFF + ((it+1)*B_+bb)*SLOTS_ + slot, lds);
}

/* write x into out[1..N]; loss/maxerr partials */
__global__ __launch_bounds__(256) void k_fin(const float* __restrict__ x,
                                             const float* __restrict__ ref,
                                             float* __restrict__ out,
                                             float* scal)
{
  __shared__ float lds[8];
  IDX_SETUP
  (void)slot;
  float4 xv = ld4(x+base);
  float4 rf = ld4(ref+base);
  /* out+1 is only 4B-aligned: scalar stores */
  out[1+base+0] = xv.x; out[1+base+1] = xv.y;
  out[1+base+2] = xv.z; out[1+base+3] = xv.w;
  float dx = xv.x-rf.x, dy = xv.y-rf.y, dz = xv.z-rf.z, dw = xv.w-rf.w;
  float loss = dx*dx + dy*dy + dz*dz + dw*dw;
  float m = fmaxf(fmaxf(fabsf(dx),fabsf(dy)), fmaxf(fabsf(dz),fabsf(dw)));
  float ls = wsum(loss);
  float mm = wmaxr(m);
  int wid = threadIdx.x >> 6, lane = threadIdx.x & 63;
  if (lane == 0) { lds[wid] = ls; lds[4+wid] = mm; }
  __syncthreads();
  if (threadIdx.x == 0) {
    atomicAdd(scal + LOSS_OFF + (flat & (SLOTS_-1)), lds[0]+lds[1]+lds[2]+lds[3]);
    float bm = fmaxf(fmaxf(lds[4],lds[5]), fmaxf(lds[6],lds[7]));
    atomicMax((unsigned int*)(scal + MAXE_OFF) + (flat & (SLOTS_-1)), __float_as_uint(bm));
  }
}

__global__ __launch_bounds__(64) void k_scal(const float* scal, float* out)
{
  int lane = threadIdx.x;
  float loss = wsum(scal[LOSS_OFF + lane]);
  float me   = wmaxr(__uint_as_float(((const unsigned int*)scal)[MAXE_OFF + lane]));
  float rho_sum = 0.f;
  for (int bb = 0; bb < B_; ++bb)
    rho_sum += wsum(scal[RHO_OFF + (ITER_*B_+bb)*SLOTS_ + lane]);
  if (lane == 0) {
    out[0]      = loss / (float)N_;
    out[1+N_]   = me;
    out[2+N_]   = rho_sum / (float)B_;
  }
}

extern "C" void kernel_launch(void* const* d_in, const int* in_sizes, int n_in,
                              void* d_out, int out_size, void* d_ws, size_t ws_size,
                              hipStream_t stream) {
  float* x         = (float*)d_in[0];        /* mutable; harness restores each launch */
  const float* b   = (const float*)d_in[1];
  const float* ref = (const float*)d_in[2];
  float* out       = (float*)d_out;

  float* r  = (float*)d_ws;
  float* p0 = r + N_;
  float* p1;
  float* scal;
  size_t need3 = ((size_t)3*N_ + SCAL_FLOATS) * sizeof(float);
  if (ws_size >= need3) {
    p1   = p0 + N_;
    scal = p1 + N_;
  } else {
    /* fall back: d_out region is scratch until k_fin (it only needs N_ floats) */
    p1   = (float*)d_out;
    scal = p0 + N_;
  }

  hipMemsetAsync(scal, 0, SCAL_FLOATS*sizeof(float), stream);

  dim3 grid(W_/16, H_, B_), blk(256);
  k_init<<<grid, blk, 0, stream>>>(x, b, r, scal);

  float* pa = p0;
  float* pb = p1;
  for (int it = 0; it < ITER_; ++it) {
    k_a<<<grid, blk, 0, stream>>>(r, (it == 0) ? r : pb, pa, scal, it, it == 0 ? 1 : 0);
    k_b<<<grid, blk, 0, stream>>>(x, r, pa, scal, it);
    float* t = pa; pa = pb; pb = t;
  }

  k_fin<<<grid, blk, 0, stream>>>(x, ref, out, scal);
  k_scal<<<1, 64, 0, stream>>>(scal, out);
}

// Round 3
// 1096.177 us; speedup vs baseline: 1.4133x; 1.4133x over previous
//
#include <hip/hip_runtime.h>

#define B_ 4
#define H_ 256
#define W_ 256
#define Z_ 64
#define NB_ (H_*W_*Z_)      /* 4194304 */
#define N_  (B_*NB_)        /* 16777216 */
#define ITER_ 8
#define EPS_ 1e-6f
#define SLOTS_ 64

/* scal layout (floats) */
#define RHO_OFF   0
#define ETA_OFF   ((ITER_+1)*B_*SLOTS_)
#define LOSS_OFF  (ETA_OFF + ITER_*B_*SLOTS_)
#define MAXE_OFF  (LOSS_OFF + SLOTS_)
#define SCAL_FLOATS (MAXE_OFF + SLOTS_)

struct F8 { float4 a, b; };

__device__ __forceinline__ float wsum(float v){
  v += __shfl_xor(v,32); v += __shfl_xor(v,16); v += __shfl_xor(v,8);
  v += __shfl_xor(v,4);  v += __shfl_xor(v,2);  v += __shfl_xor(v,1);
  return v;
}
__device__ __forceinline__ float wmaxr(float v){
  v = fmaxf(v,__shfl_xor(v,32)); v = fmaxf(v,__shfl_xor(v,16));
  v = fmaxf(v,__shfl_xor(v,8));  v = fmaxf(v,__shfl_xor(v,4));
  v = fmaxf(v,__shfl_xor(v,2));  v = fmaxf(v,__shfl_xor(v,1));
  return v;
}
__device__ __forceinline__ float read_sum(const float* s){
  return wsum(s[threadIdx.x & 63]);
}
__device__ __forceinline__ void block_atomic_sum(float v, float* dst, float* lds){
  v = wsum(v);
  int wid = threadIdx.x >> 6, lane = threadIdx.x & 63;
  if (lane == 0) lds[wid] = v;
  __syncthreads();
  if (threadIdx.x == 0) atomicAdd(dst, lds[0]+lds[1]+lds[2]+lds[3]);
}

__device__ __forceinline__ float4 ld4(const float* p){ return *(const float4*)p; }

__device__ __forceinline__ void sten_core(const F8& c, const F8& wm, const F8& wp,
                                          const F8& hm, const F8& hp,
                                          float zl, float zr, F8& st)
{
  st.a.x = 6.f*c.a.x - wm.a.x - wp.a.x - hm.a.x - hp.a.x - zl     - c.a.y;
  st.a.y = 6.f*c.a.y - wm.a.y - wp.a.y - hm.a.y - hp.a.y - c.a.x  - c.a.z;
  st.a.z = 6.f*c.a.z - wm.a.z - wp.a.z - hm.a.z - hp.a.z - c.a.y  - c.a.w;
  st.a.w = 6.f*c.a.w - wm.a.w - wp.a.w - hm.a.w - hp.a.w - c.a.z  - c.b.x;
  st.b.x = 6.f*c.b.x - wm.b.x - wp.b.x - hm.b.x - hp.b.x - c.a.w  - c.b.y;
  st.b.y = 6.f*c.b.y - wm.b.y - wp.b.y - hm.b.y - hp.b.y - c.b.x  - c.b.z;
  st.b.z = 6.f*c.b.z - wm.b.z - wp.b.z - hm.b.z - hp.b.z - c.b.y  - c.b.w;
  st.b.w = 6.f*c.b.w - wm.b.w - wp.b.w - hm.b.w - hp.b.w - c.b.z  - zr;
}

/* stencil of a single array a (8 z-elems per thread); returns center + stencil */
__device__ __forceinline__ void stencil1(const float* __restrict__ a, int base,
                                         int w, int h, int zc, F8& c, F8& st)
{
  c.a = ld4(a+base); c.b = ld4(a+base+4);
  F8 zero; zero.a = make_float4(0,0,0,0); zero.b = zero.a;
  F8 wm = zero, wp = zero, hm = zero, hp = zero;
  if (w > 0)    { wm.a = ld4(a+base-Z_);    wm.b = ld4(a+base-Z_+4); }
  if (w < W_-1) { wp.a = ld4(a+base+Z_);    wp.b = ld4(a+base+Z_+4); }
  if (h > 0)    { hm.a = ld4(a+base-W_*Z_); hm.b = ld4(a+base-W_*Z_+4); }
  if (h < H_-1) { hp.a = ld4(a+base+W_*Z_); hp.b = ld4(a+base+W_*Z_+4); }
  float zl = (zc > 0) ? a[base-1] : 0.f;
  float zr = (zc < 7) ? a[base+8] : 0.f;
  sten_core(c, wm, wp, hm, hp, zl, zr, st);
}

/* stencil of v = r + beta*p computed on the fly */
__device__ __forceinline__ F8 comb8(const float* r, const float* p, float beta, int idx){
  F8 o;
  float4 ra = ld4(r+idx), rb = ld4(r+idx+4);
  float4 pa = ld4(p+idx), pb = ld4(p+idx+4);
  o.a.x = ra.x + beta*pa.x; o.a.y = ra.y + beta*pa.y;
  o.a.z = ra.z + beta*pa.z; o.a.w = ra.w + beta*pa.w;
  o.b.x = rb.x + beta*pb.x; o.b.y = rb.y + beta*pb.y;
  o.b.z = rb.z + beta*pb.z; o.b.w = rb.w + beta*pb.w;
  return o;
}
__device__ __forceinline__ void stencil2(const float* __restrict__ r,
                                         const float* __restrict__ p, float beta,
                                         int base, int w, int h, int zc,
                                         F8& c, F8& st)
{
  c = comb8(r,p,beta,base);
  F8 zero; zero.a = make_float4(0,0,0,0); zero.b = zero.a;
  F8 wm = zero, wp = zero, hm = zero, hp = zero;
  if (w > 0)    wm = comb8(r,p,beta,base-Z_);
  if (w < W_-1) wp = comb8(r,p,beta,base+Z_);
  if (h > 0)    hm = comb8(r,p,beta,base-W_*Z_);
  if (h < H_-1) hp = comb8(r,p,beta,base+W_*Z_);
  float zl = (zc > 0) ? r[base-1] + beta*p[base-1] : 0.f;
  float zr = (zc < 7) ? r[base+8] + beta*p[base+8] : 0.f;
  sten_core(c, wm, wp, hm, hp, zl, zr, st);
}

#define IDX_SETUP \
  const int zc = threadIdx.x & 7; \
  const int wl = threadIdx.x >> 3; \
  const int w  = blockIdx.x*32 + wl; \
  const int h  = blockIdx.y; \
  const int bb = blockIdx.z; \
  const int base = ((bb*H_ + h)*W_ + w)*Z_ + zc*8; \
  const int flat = (blockIdx.z*gridDim.y + blockIdx.y)*gridDim.x + blockIdx.x; \
  const int slot = flat & (SLOTS_-1);

/* r = b - A x ; rho0 = <r,r> per batch */
__global__ __launch_bounds__(256) void k_init(const float* __restrict__ x,
                                              const float* __restrict__ b,
                                              float* __restrict__ r,
                                              float* scal)
{
  __shared__ float lds[4];
  IDX_SETUP
  F8 c, st;
  stencil1(x, base, w, h, zc, c, st);
  float4 b0 = ld4(b+base), b1 = ld4(b+base+4);
  F8 rv;
  rv.a = make_float4(b0.x-st.a.x, b0.y-st.a.y, b0.z-st.a.z, b0.w-st.a.w);
  rv.b = make_float4(b1.x-st.b.x, b1.y-st.b.y, b1.z-st.b.z, b1.w-st.b.w);
  *(float4*)(r+base)   = rv.a;
  *(float4*)(r+base+4) = rv.b;
  float rho = rv.a.x*rv.a.x + rv.a.y*rv.a.y + rv.a.z*rv.a.z + rv.a.w*rv.a.w
            + rv.b.x*rv.b.x + rv.b.y*rv.b.y + rv.b.z*rv.b.z + rv.b.w*rv.b.w;
  block_atomic_sum(rho, scal + RHO_OFF + (0*B_+bb)*SLOTS_ + slot, lds);
}

/* it==0: p = r ; eta0 = <r, A r> (single-array stencil) */
__global__ __launch_bounds__(256) void k_a0(const float* __restrict__ r,
                                            float* __restrict__ pnew,
                                            float* scal)
{
  __shared__ float lds[4];
  IDX_SETUP
  F8 c, st;
  stencil1(r, base, w, h, zc, c, st);
  *(float4*)(pnew+base)   = c.a;
  *(float4*)(pnew+base+4) = c.b;
  float eta = c.a.x*st.a.x + c.a.y*st.a.y + c.a.z*st.a.z + c.a.w*st.a.w
            + c.b.x*st.b.x + c.b.y*st.b.y + c.b.z*st.b.z + c.b.w*st.b.w;
  block_atomic_sum(eta, scal + ETA_OFF + (0*B_+bb)*SLOTS_ + slot, lds);
}

/* it>=1: p_new = r + beta*p_old ; eta = <p_new, A p_new> per batch */
__global__ __launch_bounds__(256) void k_a(const float* __restrict__ r,
                                           const float* __restrict__ pold,
                                           float* __restrict__ pnew,
                                           float* scal, int it)
{
  __shared__ float lds[4];
  IDX_SETUP
  float num = read_sum(scal + RHO_OFF + (it*B_+bb)*SLOTS_);
  float den = read_sum(scal + RHO_OFF + ((it-1)*B_+bb)*SLOTS_);
  float beta = num / (den + EPS_);
  F8 c, st;
  stencil2(r, pold, beta, base, w, h, zc, c, st);
  *(float4*)(pnew+base)   = c.a;
  *(float4*)(pnew+base+4) = c.b;
  float eta = c.a.x*st.a.x + c.a.y*st.a.y + c.a.z*st.a.z + c.a.w*st.a.w
            + c.b.x*st.b.x + c.b.y*st.b.y + c.b.z*st.b.z + c.b.w*st.b.w;
  block_atomic_sum(eta, scal + ETA_OFF + (it*B_+bb)*SLOTS_ + slot, lds);
}

/* it<7: alpha; x += alpha p; r -= alpha*A p; rho_next = <r,r> */
__global__ __launch_bounds__(256) void k_b(float* __restrict__ x,
                                           float* __restrict__ r,
                                           const float* __restrict__ p,
                                           float* scal, int it)
{
  __shared__ float lds[4];
  IDX_SETUP
  float num = read_sum(scal + RHO_OFF + (it*B_+bb)*SLOTS_);
  float den = read_sum(scal + ETA_OFF + (it*B_+bb)*SLOTS_);
  float alpha = num / (den + EPS_);
  F8 c, st;
  stencil1(p, base, w, h, zc, c, st);
  float4 x0 = ld4(x+base), x1 = ld4(x+base+4);
  x0.x += alpha*c.a.x; x0.y += alpha*c.a.y; x0.z += alpha*c.a.z; x0.w += alpha*c.a.w;
  x1.x += alpha*c.b.x; x1.y += alpha*c.b.y; x1.z += alpha*c.b.z; x1.w += alpha*c.b.w;
  *(float4*)(x+base)   = x0;
  *(float4*)(x+base+4) = x1;
  float4 r0 = ld4(r+base), r1 = ld4(r+base+4);
  r0.x -= alpha*st.a.x; r0.y -= alpha*st.a.y; r0.z -= alpha*st.a.z; r0.w -= alpha*st.a.w;
  r1.x -= alpha*st.b.x; r1.y -= alpha*st.b.y; r1.z -= alpha*st.b.z; r1.w -= alpha*st.b.w;
  *(float4*)(r+base)   = r0;
  *(float4*)(r+base+4) = r1;
  float rho = r0.x*r0.x + r0.y*r0.y + r0.z*r0.z + r0.w*r0.w
            + r1.x*r1.x + r1.y*r1.y + r1.z*r1.z + r1.w*r1.w;
  block_atomic_sum(rho, scal + RHO_OFF + ((it+1)*B_+bb)*SLOTS_ + slot, lds);
}

/* it==7 fused with epilogue: x_new/r_new in registers only; writes out[1..N]
   via LDS-staged ALIGNED float4 stores; loss/maxerr/rho8 partials. */
__global__ __launch_bounds__(256) void k_b_fin(const float* __restrict__ x,
                                               const float* __restrict__ r,
                                               const float* __restrict__ p,
                                               const float* __restrict__ ref,
                                               float* __restrict__ out,
                                               float* scal, int it)
{
  __shared__ float xs[2048];
  __shared__ float lds[12];
  IDX_SETUP
  float num = read_sum(scal + RHO_OFF + (it*B_+bb)*SLOTS_);
  float den = read_sum(scal + ETA_OFF + (it*B_+bb)*SLOTS_);
  float alpha = num / (den + EPS_);
  F8 c, st;
  stencil1(p, base, w, h, zc, c, st);
  float4 x0 = ld4(x+base), x1 = ld4(x+base+4);
  x0.x += alpha*c.a.x; x0.y += alpha*c.a.y; x0.z += alpha*c.a.z; x0.w += alpha*c.a.w;
  x1.x += alpha*c.b.x; x1.y += alpha*c.b.y; x1.z += alpha*c.b.z; x1.w += alpha*c.b.w;
  float4 r0 = ld4(r+base), r1 = ld4(r+base+4);
  r0.x -= alpha*st.a.x; r0.y -= alpha*st.a.y; r0.z -= alpha*st.a.z; r0.w -= alpha*st.a.w;
  r1.x -= alpha*st.b.x; r1.y -= alpha*st.b.y; r1.z -= alpha*st.b.z; r1.w -= alpha*st.b.w;
  float rho = r0.x*r0.x + r0.y*r0.y + r0.z*r0.z + r0.w*r0.w
            + r1.x*r1.x + r1.y*r1.y + r1.z*r1.z + r1.w*r1.w;

  /* stage x_new to LDS for aligned out stores */
  const int t = threadIdx.x;
  xs[t*8+0] = x0.x; xs[t*8+1] = x0.y; xs[t*8+2] = x0.z; xs[t*8+3] = x0.w;
  xs[t*8+4] = x1.x; xs[t*8+5] = x1.y; xs[t*8+6] = x1.z; xs[t*8+7] = x1.w;

  /* loss / maxerr vs reference */
  float4 f0 = ld4(ref+base), f1 = ld4(ref+base+4);
  float d0 = x0.x-f0.x, d1 = x0.y-f0.y, d2 = x0.z-f0.z, d3 = x0.w-f0.w;
  float d4 = x1.x-f1.x, d5 = x1.y-f1.y, d6 = x1.z-f1.z, d7 = x1.w-f1.w;
  float loss = d0*d0+d1*d1+d2*d2+d3*d3+d4*d4+d5*d5+d6*d6+d7*d7;
  float me = fmaxf(fmaxf(fmaxf(fabsf(d0),fabsf(d1)),fmaxf(fabsf(d2),fabsf(d3))),
                   fmaxf(fmaxf(fabsf(d4),fabsf(d5)),fmaxf(fabsf(d6),fabsf(d7))));

  float rs = wsum(rho), ls = wsum(loss), ms = wmaxr(me);
  int wid = t >> 6, lane = t & 63;
  if (lane == 0) { lds[wid] = rs; lds[4+wid] = ls; lds[8+wid] = ms; }
  __syncthreads();
  if (t == 0) {
    atomicAdd(scal + RHO_OFF + ((it+1)*B_+bb)*SLOTS_ + slot, lds[0]+lds[1]+lds[2]+lds[3]);
    atomicAdd(scal + LOSS_OFF + slot, lds[4]+lds[5]+lds[6]+lds[7]);
    float bm = fmaxf(fmaxf(lds[8],lds[9]), fmaxf(lds[10],lds[11]));
    atomicMax((unsigned int*)(scal + MAXE_OFF) + slot, __float_as_uint(bm));
  }

  /* aligned stores: block's x-flat span is [S, S+2048), out span [1+S, 2048+S] */
  const int S = flat * 2048;
  #pragma unroll
  for (int c2 = 0; c2 < 2; ++c2) {
    int q = t + 256*c2;
    if (q < 511) {
      float4 v = make_float4(xs[3+4*q], xs[4+4*q], xs[5+4*q], xs[6+4*q]);
      *(float4*)(out + S + 4 + 4*q) = v;
    } else if (q == 511) {
      out[S+1] = xs[0]; out[S+2] = xs[1]; out[S+3] = xs[2];
      out[S+2048] = xs[2047];
    }
  }
}

__global__ __launch_bounds__(64) void k_scal(const float* scal, float* out)
{
  int lane = threadIdx.x;
  float loss = wsum(scal[LOSS_OFF + lane]);
  float me   = wmaxr(__uint_as_float(((const unsigned int*)scal)[MAXE_OFF + lane]));
  float rho_sum = 0.f;
  for (int bb = 0; bb < B_; ++bb)
    rho_sum += wsum(scal[RHO_OFF + (ITER_*B_+bb)*SLOTS_ + lane]);
  if (lane == 0) {
    out[0]      = loss / (float)N_;
    out[1+N_]   = me;
    out[2+N_]   = rho_sum / (float)B_;
  }
}

extern "C" void kernel_launch(void* const* d_in, const int* in_sizes, int n_in,
                              void* d_out, int out_size, void* d_ws, size_t ws_size,
                              hipStream_t stream) {
  float* x         = (float*)d_in[0];
  const float* b   = (const float*)d_in[1];
  const float* ref = (const float*)d_in[2];
  float* out       = (float*)d_out;

  float* r  = (float*)d_ws;
  float* p0 = r + N_;
  float* p1;
  float* scal;
  size_t need3 = ((size_t)3*N_ + SCAL_FLOATS) * sizeof(float);
  if (ws_size >= need3) {
    p1   = p0 + N_;
    scal = p1 + N_;
  } else {
    /* fallback: d_out is scratch until the final kernel.  Parity below
       guarantees the final iteration reads p0 (real ws), never d_out. */
    p1   = (float*)d_out;
    scal = p0 + N_;
  }

  (void)hipMemsetAsync(scal, 0, SCAL_FLOATS*sizeof(float), stream);

  dim3 grid(W_/32, H_, B_), blk(256);
  k_init<<<grid, blk, 0, stream>>>(x, b, r, scal);

  /* start with pa=p1 so that it=7 (even # of swaps later) lands on p0 */
  float* pa = p1;
  float* pb = p0;
  for (int it = 0; it < ITER_; ++it) {
    if (it == 0)
      k_a0<<<grid, blk, 0, stream>>>(r, pa, scal);
    else
      k_a<<<grid, blk, 0, stream>>>(r, pb, pa, scal, it);
    if (it < ITER_-1)
      k_b<<<grid, blk, 0, stream>>>(x, r, pa, scal, it);
    else
      k_b_fin<<<grid, blk, 0, stream>>>(x, r, pa, ref, out, scal, it);
    float* t = pa; pa = pb; pb = t;
  }

  k_scal<<<1, 64, 0, stream>>>(scal, out);
}